// Round 7
// baseline (402.927 us; speedup 1.0000x reference)
//
#include <hip/hip_runtime.h>

// DilateAttention: B=4, d=384 (12 heads x 32), H=W=64, 3x3 taps, dilation 2, pad 2.
// f32 in / f32 out.
// v8: v1's traffic-clean geometry (1 px/thread, 4-row blocks, grid 768, no
// swizzle, per-lane 128-B stores) + deep load batching the compiler will
// actually honor.
//   - v7 lesson: launch_bounds(256,3) is only a MIN; compiler chose the
//     6-wave/EU tier (VGPR 84) and spilled the batch arrays to scratch
//     (WRITE +18 MB, FETCH +9 MB, 47->73 us). Fix: amdgpu_waves_per_eu(3,3)
//     pins min AND max -> full ~170-reg budget, no spill incentive.
//   - Loop order ch-group(4)-outer / tap-inner: 36 independent loads per
//     batch into static arrays, 9 independent logit accumulators. Phase 2
//     computes o[4] per group and stores its float4 immediately (low pressure).
//   - Occupancy is grid-limited (768 blocks = 3/CU = 12 waves/CU) so the
//     3-waves/EU cap costs nothing.

#define NHD  12
#define DDIM 384
#define HH   64
#define WW   64
#define HWSZ 4096
#define SCALEF 0.17677669529663687f  // 1/sqrt(32)

// block = 256: 4 y-rows x 64 x-lanes. grid = B*NH*(H/4) = 768.
__global__ __launch_bounds__(256) __attribute__((amdgpu_waves_per_eu(3, 3)))
void dilate_attn(const float* __restrict__ q,
                 const float* __restrict__ k,
                 const float* __restrict__ v,
                 float* __restrict__ out) {
    const int tid = threadIdx.x;
    const int r   = tid >> 6;          // 0..3
    const int x   = tid & 63;
    const int bz  = blockIdx.x;
    const int bh  = bz >> 4;           // b*NH + n
    const int b   = bh / NHD;
    const int n   = bh - b * NHD;
    const int y   = (bz & 15) * 4 + r;

    const int cbase = (b * DDIM + n * 32) * HWSZ;   // 32-bit indexing
    const int pix   = y * WW + x;

    // 9 tap offsets, clamped to center when OOB; validity recorded separately.
    int  toff[9];
    bool tval[9];
#pragma unroll
    for (int di = 0; di < 3; ++di) {
        int yy = y + 2 * di - 2;
        bool vy = (yy >= 0) && (yy < HH);
#pragma unroll
        for (int p = 0; p < 3; ++p) {
            int xo = x + 2 * p - 2;
            bool ok = vy && (xo >= 0) && (xo < WW);
            tval[di * 3 + p] = ok;
            toff[di * 3 + p] = ok ? (yy * WW + xo) : pix;   // clamped: in-bounds
        }
    }

    // ---------------- preload q (scale folded in) ----------------
    float qreg[32];
#pragma unroll
    for (int c = 0; c < 32; ++c) qreg[c] = q[cbase + pix + c * HWSZ] * SCALEF;

    // ---------------- Phase 1: logits; 4-ch batches of 36 independent loads -
    float l[9];
#pragma unroll
    for (int t = 0; t < 9; ++t) l[t] = 0.f;
#pragma unroll
    for (int cg = 0; cg < 8; ++cg) {
        float kb[4][9];
#pragma unroll
        for (int j = 0; j < 4; ++j) {
            const int base = cbase + (cg * 4 + j) * HWSZ;
#pragma unroll
            for (int t = 0; t < 9; ++t) kb[j][t] = k[base + toff[t]];
        }
#pragma unroll
        for (int t = 0; t < 9; ++t)
            l[t] += qreg[cg * 4]     * kb[0][t] + qreg[cg * 4 + 1] * kb[1][t]
                  + qreg[cg * 4 + 2] * kb[2][t] + qreg[cg * 4 + 3] * kb[3][t];
    }

    // ---------------- Softmax over 9 (zero-pad taps -> logit 0) -------------
#pragma unroll
    for (int t = 0; t < 9; ++t) l[t] = tval[t] ? l[t] : 0.f;
    float m = l[0];
#pragma unroll
    for (int t = 1; t < 9; ++t) m = fmaxf(m, l[t]);
    float w[9], s = 0.f;
#pragma unroll
    for (int t = 0; t < 9; ++t) { w[t] = __expf(l[t] - m); s += w[t]; }
    float inv = 1.0f / s;
#pragma unroll
    for (int t = 0; t < 9; ++t) w[t] = tval[t] ? (w[t] * inv) : 0.f;  // padded V == 0

    // ---------------- Phase 2: weighted V; 4-ch batches, store immediately --
    const int ob = (b * HH * WW + pix) * DDIM + n * 32;
#pragma unroll
    for (int cg = 0; cg < 8; ++cg) {
        float vb[4][9];
#pragma unroll
        for (int j = 0; j < 4; ++j) {
            const int base = cbase + (cg * 4 + j) * HWSZ;
#pragma unroll
            for (int t = 0; t < 9; ++t) vb[j][t] = v[base + toff[t]];
        }
        float o0 = 0.f, o1 = 0.f, o2 = 0.f, o3 = 0.f;
#pragma unroll
        for (int t = 0; t < 9; ++t) {
            const float wt = w[t];
            o0 += wt * vb[0][t];
            o1 += wt * vb[1][t];
            o2 += wt * vb[2][t];
            o3 += wt * vb[3][t];
        }
        *(float4*)(out + ob + cg * 4) = make_float4(o0, o1, o2, o3);
    }
}

extern "C" void kernel_launch(void* const* d_in, const int* in_sizes, int n_in,
                              void* d_out, int out_size, void* d_ws, size_t ws_size,
                              hipStream_t stream) {
    const float* q = (const float*)d_in[0];
    const float* k = (const float*)d_in[1];
    const float* v = (const float*)d_in[2];
    float* out = (float*)d_out;
    hipLaunchKernelGGL(dilate_attn, dim3(768), dim3(256), 0, stream, q, k, v, out);
}

// Round 8
// 124.705 us; speedup vs baseline: 3.2310x; 3.2310x over previous
//
#include <hip/hip_runtime.h>

// DilateAttention: B=4, d=384 (12 heads x 32), H=W=64, 3x3 taps, dilation 2, pad 2.
// f32 in / f32 out.
// v9: v1 geometry + shuffle-gathered x-taps.
// Evidence v1-v8:
//   - v1 (1 px/thread, 4-row blocks, grid 768, per-lane 128-B stores) is the
//     only traffic-clean config (FETCH 60 MB, WRITE 32 MB) at 47 us; limit is
//     608 scalar tap loads/thread, ~1 VMEM/15 cy/CU, VALUBusy 15%.
//   - Adding waves (v2-v5) thrashes L2; LDS staging (v6) over-serializes;
//     register-array load batching (v7/v8) spills — allocator pins ~84 VGPR
//     and will not go higher for this kernel.
// v9 cuts VMEM 2.7x with zero extra register arrays: lane = x, so the x+-2
// taps are neighbors' center values. Per (channel, tap-row): ONE coalesced
// dword load + shfl_up/down by 2 lanes (DS pipe, parallel to VMEM).
//   k: 288->96 loads, v: 288->96, q: 32. Total 224 VMEM/thread.
// Edge lanes (x<2, x>61): shfl returns self -> garbage taps, but those taps
// are tval-gated to logit 0 / weight 0 exactly as v1. y-edge rows clamped and
// gated as v1. Store pattern bit-identical to v1.

#define NHD  12
#define DDIM 384
#define HH   64
#define WW   64
#define HWSZ 4096
#define SCALEF 0.17677669529663687f  // 1/sqrt(32)

// block = 256: 4 y-rows x 64 x-lanes. grid = B*NH*(H/4) = 768.
__global__ __launch_bounds__(256) void dilate_attn(const float* __restrict__ q,
                                                   const float* __restrict__ k,
                                                   const float* __restrict__ v,
                                                   float* __restrict__ out) {
    const int tid = threadIdx.x;
    const int r   = tid >> 6;          // 0..3
    const int x   = tid & 63;
    const int bz  = blockIdx.x;
    const int bh  = bz >> 4;           // b*NH + n
    const int b   = bh / NHD;
    const int n   = bh - b * NHD;
    const int y   = (bz & 15) * 4 + r;

    const int cbase = (b * DDIM + n * 32) * HWSZ;   // 32-bit indexing
    const int pix   = y * WW + x;

    // 3 tap-row offsets (y-clamped, gated) + x-edge validity.
    int  rowoff[3];
    bool vy[3];
#pragma unroll
    for (int di = 0; di < 3; ++di) {
        int yy = y + 2 * di - 2;
        vy[di] = (yy >= 0) && (yy < HH);
        yy = yy < 0 ? 0 : (yy > 63 ? 63 : yy);
        rowoff[di] = yy * WW + x;      // this lane's column in the tap row
    }
    const bool vxm = (x >= 2);
    const bool vxp = (x <= 61);
    bool tval[9];
#pragma unroll
    for (int di = 0; di < 3; ++di) {
        tval[di * 3 + 0] = vy[di] && vxm;
        tval[di * 3 + 1] = vy[di];
        tval[di * 3 + 2] = vy[di] && vxp;
    }

    // ---------------- preload q (scale folded in) ----------------
    float qreg[32];
#pragma unroll
    for (int c = 0; c < 32; ++c) qreg[c] = q[cbase + pix + c * HWSZ] * SCALEF;

    // ---------------- Phase 1: logits; 1 load + 2 shuffles per (ch,row) -----
    float l[9];
#pragma unroll
    for (int t = 0; t < 9; ++t) l[t] = 0.f;
#pragma unroll
    for (int c = 0; c < 32; ++c) {
        const int base = cbase + c * HWSZ;
        const float qc = qreg[c];
#pragma unroll
        for (int di = 0; di < 3; ++di) {
            const float kc = k[base + rowoff[di]];
            const float km = __shfl_up(kc, 2);     // k[row, x-2]
            const float kp = __shfl_down(kc, 2);   // k[row, x+2]
            l[di * 3 + 0] += qc * km;
            l[di * 3 + 1] += qc * kc;
            l[di * 3 + 2] += qc * kp;
        }
    }

    // ---------------- Softmax over 9 (invalid taps -> logit 0) --------------
#pragma unroll
    for (int t = 0; t < 9; ++t) l[t] = tval[t] ? l[t] : 0.f;
    float m = l[0];
#pragma unroll
    for (int t = 1; t < 9; ++t) m = fmaxf(m, l[t]);
    float w[9], s = 0.f;
#pragma unroll
    for (int t = 0; t < 9; ++t) { w[t] = __expf(l[t] - m); s += w[t]; }
    float inv = 1.0f / s;
#pragma unroll
    for (int t = 0; t < 9; ++t) w[t] = tval[t] ? (w[t] * inv) : 0.f;  // padded V == 0

    // ---------------- Phase 2: weighted V; 1 load + 2 shuffles per (ch,row) -
    float o[32];
#pragma unroll
    for (int c = 0; c < 32; ++c) o[c] = 0.f;
#pragma unroll
    for (int c = 0; c < 32; ++c) {
        const int base = cbase + c * HWSZ;
        float acc = 0.f;
#pragma unroll
        for (int di = 0; di < 3; ++di) {
            const float vc = v[base + rowoff[di]];
            const float vm = __shfl_up(vc, 2);     // v[row, x-2]
            const float vp = __shfl_down(vc, 2);   // v[row, x+2]
            acc += w[di * 3 + 0] * vm + w[di * 3 + 1] * vc + w[di * 3 + 2] * vp;
        }
        o[c] = acc;
    }

    // ---------------- Output: lane owns the full 128-B head chunk -----------
    const int ob = (b * HH * WW + pix) * DDIM + n * 32;
#pragma unroll
    for (int j = 0; j < 8; ++j)
        *(float4*)(out + ob + j * 4) =
            make_float4(o[j * 4], o[j * 4 + 1], o[j * 4 + 2], o[j * 4 + 3]);
}

extern "C" void kernel_launch(void* const* d_in, const int* in_sizes, int n_in,
                              void* d_out, int out_size, void* d_ws, size_t ws_size,
                              hipStream_t stream) {
    const float* q = (const float*)d_in[0];
    const float* k = (const float*)d_in[1];
    const float* v = (const float*)d_in[2];
    float* out = (float*)d_out;
    hipLaunchKernelGGL(dilate_attn, dim3(768), dim3(256), 0, stream, q, k, v, out);
}

// Round 9
// 118.845 us; speedup vs baseline: 3.3904x; 1.0493x over previous
//
#include <hip/hip_runtime.h>

// DilateAttention: B=4, d=384 (12 heads x 32), H=W=64, 3x3 taps, dilation 2, pad 2.
// f32 in / f32 out.
// v10: occupancy 2x via wave-level channel split, with the v1-v9 dataset
// re-explained: ALL "traffic blowups" (v2-v8) were register-allocator SPILL
// caused by the second __launch_bounds__/waves_per_eu arg capping VGPR at
// 40/84; geometry was never the culprit. v1/v9 (plain bounds, VGPR 104/120)
// are spill-free and traffic-clean, but run at only ~2 TB/s effective because
// 12 waves/CU can't fill the HBM latency-BW product (v4 reached 3.4 TB/s at
// 24 waves/CU even while spilling).
//   - 2 threads/px: wave = (row r, channel-half hg); each wave spans a full
//     64-x row so v9's x-shuffle tap gather still works; loads fully disjoint.
//   - logit halves combined through 9.2 KB LDS (stride 9 => 2-way, free) +
//     one barrier; softmax redundant per half (cheap).
//   - v3-proven bijective XCD swizzle (1536 = 8 x 192) for halo L2 locality.
//   - PLAIN __launch_bounds__(256): allocator free => no spill (~60-90 regs).

#define NHD  12
#define DDIM 384
#define HH   64
#define WW   64
#define HWSZ 4096
#define SCALEF 0.17677669529663687f  // 1/sqrt(32)

// block = 256 = 4 waves: wave w -> r = w&1 (row of pair), hg = w>>1 (ch half).
// grid = B*NH*(H/2) = 1536 = 8 XCDs x 192 contiguous logical blocks.
__global__ __launch_bounds__(256) void dilate_attn(const float* __restrict__ q,
                                                   const float* __restrict__ k,
                                                   const float* __restrict__ v,
                                                   float* __restrict__ out) {
    __shared__ float lbuf[2][2][64][9];   // [hg][r][x][tap] = 9216 B

    const int tid = threadIdx.x;
    const int x   = tid & 63;
    const int w4  = tid >> 6;
    const int r   = w4 & 1;              // row within the pair
    const int hg  = w4 >> 1;             // channel half (16 ch)

    // XCD swizzle: contiguous 192-logical-block chunk per XCD (bijective).
    const int phys = blockIdx.x;
    const int lz   = (phys & 7) * 192 + (phys >> 3);

    const int bh = lz >> 5;              // b*NH + n
    const int y  = (lz & 31) * 2 + r;
    const int b  = bh / NHD;
    const int n  = bh - b * NHD;

    const int cbase = (b * DDIM + n * 32 + hg * 16) * HWSZ;  // 32-bit indexing
    const int pix   = y * WW + x;

    // 3 tap-row offsets (y-clamped, gated) + x-edge validity (v9 pattern).
    int  rowoff[3];
    bool vy[3];
#pragma unroll
    for (int di = 0; di < 3; ++di) {
        int yy = y + 2 * di - 2;
        vy[di] = (yy >= 0) && (yy < HH);
        yy = yy < 0 ? 0 : (yy > 63 ? 63 : yy);
        rowoff[di] = yy * WW + x;
    }
    const bool vxm = (x >= 2);
    const bool vxp = (x <= 61);
    bool tval[9];
#pragma unroll
    for (int di = 0; di < 3; ++di) {
        tval[di * 3 + 0] = vy[di] && vxm;
        tval[di * 3 + 1] = vy[di];
        tval[di * 3 + 2] = vy[di] && vxp;
    }

    // ---------------- preload q half (scale folded in) ----------------
    float qreg[16];
#pragma unroll
    for (int c = 0; c < 16; ++c) qreg[c] = q[cbase + pix + c * HWSZ] * SCALEF;

    // ------- Phase 1: partial logits; 1 coalesced load + 2 shfl per (ch,row)
    float l[9];
#pragma unroll
    for (int t = 0; t < 9; ++t) l[t] = 0.f;
#pragma unroll
    for (int c = 0; c < 16; ++c) {
        const int base = cbase + c * HWSZ;
        const float qc = qreg[c];
#pragma unroll
        for (int di = 0; di < 3; ++di) {
            const float kc = k[base + rowoff[di]];
            const float km = __shfl_up(kc, 2);     // k[row, x-2]
            const float kp = __shfl_down(kc, 2);   // k[row, x+2]
            l[di * 3 + 0] += qc * km;
            l[di * 3 + 1] += qc * kc;
            l[di * 3 + 2] += qc * kp;
        }
    }

    // ------- combine the two channel halves through LDS (one barrier) -------
#pragma unroll
    for (int t = 0; t < 9; ++t) lbuf[hg][r][x][t] = l[t];
    __syncthreads();
#pragma unroll
    for (int t = 0; t < 9; ++t) l[t] += lbuf[hg ^ 1][r][x][t];

    // ---------------- Softmax over 9 (invalid taps -> logit 0) --------------
#pragma unroll
    for (int t = 0; t < 9; ++t) l[t] = tval[t] ? l[t] : 0.f;
    float m = l[0];
#pragma unroll
    for (int t = 1; t < 9; ++t) m = fmaxf(m, l[t]);
    float wgt[9], s = 0.f;
#pragma unroll
    for (int t = 0; t < 9; ++t) { wgt[t] = __expf(l[t] - m); s += wgt[t]; }
    float inv = 1.0f / s;
#pragma unroll
    for (int t = 0; t < 9; ++t) wgt[t] = tval[t] ? (wgt[t] * inv) : 0.f;  // pad V == 0

    // ------- Phase 2: weighted V over own 16 channels (load + 2 shfl) -------
    float o[16];
#pragma unroll
    for (int c = 0; c < 16; ++c) {
        const int base = cbase + c * HWSZ;
        float acc = 0.f;
#pragma unroll
        for (int di = 0; di < 3; ++di) {
            const float vc = v[base + rowoff[di]];
            const float vm = __shfl_up(vc, 2);     // v[row, x-2]
            const float vp = __shfl_down(vc, 2);   // v[row, x+2]
            acc += wgt[di * 3 + 0] * vm + wgt[di * 3 + 1] * vc + wgt[di * 3 + 2] * vp;
        }
        o[c] = acc;
    }

    // ---------------- Output: lane owns 64 contiguous bytes -----------------
    const int ob = (b * HH * WW + pix) * DDIM + n * 32 + hg * 16;
#pragma unroll
    for (int j = 0; j < 4; ++j)
        *(float4*)(out + ob + j * 4) =
            make_float4(o[j * 4], o[j * 4 + 1], o[j * 4 + 2], o[j * 4 + 3]);
}

extern "C" void kernel_launch(void* const* d_in, const int* in_sizes, int n_in,
                              void* d_out, int out_size, void* d_ws, size_t ws_size,
                              hipStream_t stream) {
    const float* q = (const float*)d_in[0];
    const float* k = (const float*)d_in[1];
    const float* v = (const float*)d_in[2];
    float* out = (float*)d_out;
    hipLaunchKernelGGL(dilate_attn, dim3(1536), dim3(256), 0, stream, q, k, v, out);
}

// Round 10
// 118.452 us; speedup vs baseline: 3.4016x; 1.0033x over previous
//
#include <hip/hip_runtime.h>

// DilateAttention: B=4, d=384 (12 heads x 32), H=W=64, 3x3 taps, dilation 2, pad 2.
// f32 in / f32 out.
// v11: float4 work unit (4 px/thread) — load-DENSITY fix.
// Ladder so far: v1 47us (scalar, 12 w/CU) -> v10 42.6us (scalar, 24 w/CU,
// clean traffic, VGPR 68). v10 showed wave count alone doesn't help: scalar
// dword loads (256 B/instr) can't build enough outstanding bytes (Little's
// law needs ~3-5 KB/CU in flight; VGPR-68 waves hold ~2 KB total).
// v11: one dwordx4 = 1 KB/instr (4x). Wave = one row: 16 px-lanes (4 px each)
// x 4 channel-groups (8 ch). x+-2 taps from own float4 components + 2 comps
// shfl'd from lane+-1 (invalid edge taps tval-gated as always). Cross-cg QK
// reduce via shfl_xor(16/32) in-register — NO LDS, NO barriers anywhere.
// Per-thread VMEM: 8 q + 24 k + 24 v + 8 st = 64 instrs (v10: ~120), 4x denser.
// Plain __launch_bounds__(256): allocator free, no spill (v7/v8 lesson).
// grid = B*NH*(H/4) = 768 = 8 XCDs x 96 contiguous (bijective swizzle).

#define NHD  12
#define DDIM 384
#define HH   64
#define WW   64
#define HWSZ 4096
#define SCALEF 0.17677669529663687f  // 1/sqrt(32)

__global__ __launch_bounds__(256) void dilate_attn(const float* __restrict__ q,
                                                   const float* __restrict__ k,
                                                   const float* __restrict__ v,
                                                   float* __restrict__ out) {
    const int tid  = threadIdx.x;
    const int lane = tid & 63;
    const int i16  = lane & 15;          // px-group within row
    const int cg   = (lane >> 4) & 3;    // channel group (8 ch)
    const int wv   = tid >> 6;           // wave = row within 4-row strip
    const int x0   = i16 * 4;            // first of 4 owned pixels

    // XCD swizzle: 768 = 8 XCDs x 96 contiguous logical blocks (bijective).
    const int phys = blockIdx.x;
    const int lz   = (phys & 7) * 96 + (phys >> 3);

    const int bh = lz >> 4;              // b*NH + n
    const int y  = (lz & 15) * 4 + wv;
    const int b  = bh / NHD;
    const int n  = bh - b * NHD;

    const int cbase = (b * DDIM + n * 32 + cg * 8) * HWSZ;  // 32-bit indexing
    const int prow  = y * WW;

    // 3 tap-row offsets (y-clamped, gated later).
    int  rowoff[3];
    bool vy[3];
#pragma unroll
    for (int di = 0; di < 3; ++di) {
        int yy = y + 2 * di - 2;
        vy[di] = (yy >= 0) && (yy < HH);
        yy = yy < 0 ? 0 : (yy > 63 ? 63 : yy);
        rowoff[di] = yy * WW + x0;
    }

    // ---------------- preload q (scale folded in): 8 ch x 4 px --------------
    float4 qv[8];
#pragma unroll
    for (int c = 0; c < 8; ++c) {
        float4 t = *(const float4*)(q + cbase + c * HWSZ + prow + x0);
        qv[c] = make_float4(t.x * SCALEF, t.y * SCALEF, t.z * SCALEF, t.w * SCALEF);
    }

    // ---------------- Phase 1: logits; 1 dwordx4 + 4 shfl per (ch,row) ------
    // Tap values for px p (global x = x0+p):  L(eft,-2) C(enter) R(ight,+2)
    //   p0: L=lane-1.z  C=own.x  R=own.z      p1: L=lane-1.w  C=own.y  R=own.w
    //   p2: L=own.x     C=own.z  R=lane+1.x   p3: L=own.y     C=own.w  R=lane+1.y
    float l[4][9];
#pragma unroll
    for (int p = 0; p < 4; ++p)
#pragma unroll
        for (int t = 0; t < 9; ++t) l[p][t] = 0.f;

#pragma unroll
    for (int c = 0; c < 8; ++c) {
#pragma unroll
        for (int di = 0; di < 3; ++di) {
            const float4 kv = *(const float4*)(k + cbase + c * HWSZ + rowoff[di]);
            const float km2 = __shfl_up(kv.z, 1);    // x0-2
            const float km1 = __shfl_up(kv.w, 1);    // x0-1
            const float kp4 = __shfl_down(kv.x, 1);  // x0+4
            const float kp5 = __shfl_down(kv.y, 1);  // x0+5
            const int t0 = di * 3;
            l[0][t0+0] += qv[c].x * km2;  l[0][t0+1] += qv[c].x * kv.x;  l[0][t0+2] += qv[c].x * kv.z;
            l[1][t0+0] += qv[c].y * km1;  l[1][t0+1] += qv[c].y * kv.y;  l[1][t0+2] += qv[c].y * kv.w;
            l[2][t0+0] += qv[c].z * kv.x; l[2][t0+1] += qv[c].z * kv.z;  l[2][t0+2] += qv[c].z * kp4;
            l[3][t0+0] += qv[c].w * kv.y; l[3][t0+1] += qv[c].w * kv.w;  l[3][t0+2] += qv[c].w * kp5;
        }
    }

    // ---- butterfly reduce across the 4 channel groups (lane bits 4,5) ------
#pragma unroll
    for (int p = 0; p < 4; ++p)
#pragma unroll
        for (int t = 0; t < 9; ++t) {
            l[p][t] += __shfl_xor(l[p][t], 16, 64);
            l[p][t] += __shfl_xor(l[p][t], 32, 64);
        }

    // ---------------- Softmax per px (invalid taps gated), in place ---------
#pragma unroll
    for (int p = 0; p < 4; ++p) {
        const int xg = x0 + p;
        const bool vxm = (xg >= 2), vxp = (xg <= 61);
        bool tv[9];
#pragma unroll
        for (int di = 0; di < 3; ++di) {
            tv[di * 3 + 0] = vy[di] && vxm;
            tv[di * 3 + 1] = vy[di];
            tv[di * 3 + 2] = vy[di] && vxp;
        }
#pragma unroll
        for (int t = 0; t < 9; ++t) l[p][t] = tv[t] ? l[p][t] : 0.f;
        float m = l[p][0];
#pragma unroll
        for (int t = 1; t < 9; ++t) m = fmaxf(m, l[p][t]);
        float s = 0.f;
#pragma unroll
        for (int t = 0; t < 9; ++t) { l[p][t] = __expf(l[p][t] - m); s += l[p][t]; }
        const float inv = 1.0f / s;
#pragma unroll
        for (int t = 0; t < 9; ++t) l[p][t] = tv[t] ? (l[p][t] * inv) : 0.f;  // pad V == 0
    }

    // ---------------- Phase 2: weighted V; 1 dwordx4 + 4 shfl per (ch,row) --
    float o[8][4];
#pragma unroll
    for (int c = 0; c < 8; ++c)
#pragma unroll
        for (int p = 0; p < 4; ++p) o[c][p] = 0.f;

#pragma unroll
    for (int c = 0; c < 8; ++c) {
#pragma unroll
        for (int di = 0; di < 3; ++di) {
            const float4 vv = *(const float4*)(v + cbase + c * HWSZ + rowoff[di]);
            const float vm2 = __shfl_up(vv.z, 1);
            const float vm1 = __shfl_up(vv.w, 1);
            const float vp4 = __shfl_down(vv.x, 1);
            const float vp5 = __shfl_down(vv.y, 1);
            const int t0 = di * 3;
            o[c][0] += l[0][t0] * vm2  + l[0][t0+1] * vv.x + l[0][t0+2] * vv.z;
            o[c][1] += l[1][t0] * vm1  + l[1][t0+1] * vv.y + l[1][t0+2] * vv.w;
            o[c][2] += l[2][t0] * vv.x + l[2][t0+1] * vv.z + l[2][t0+2] * vp4;
            o[c][3] += l[3][t0] * vv.y + l[3][t0+1] * vv.w + l[3][t0+2] * vp5;
        }
    }

    // ---------------- Output: per px, 32 contiguous bytes (2 x float4) ------
#pragma unroll
    for (int p = 0; p < 4; ++p) {
        const int ob = (b * (HH * WW) + prow + x0 + p) * DDIM + n * 32 + cg * 8;
        *(float4*)(out + ob)     = make_float4(o[0][p], o[1][p], o[2][p], o[3][p]);
        *(float4*)(out + ob + 4) = make_float4(o[4][p], o[5][p], o[6][p], o[7][p]);
    }
}

extern "C" void kernel_launch(void* const* d_in, const int* in_sizes, int n_in,
                              void* d_out, int out_size, void* d_ws, size_t ws_size,
                              hipStream_t stream) {
    const float* q = (const float*)d_in[0];
    const float* k = (const float*)d_in[1];
    const float* v = (const float*)d_in[2];
    float* out = (float*)d_out;
    hipLaunchKernelGGL(dilate_attn, dim3(768), dim3(256), 0, stream, q, k, v, out);
}

// Round 11
// 116.801 us; speedup vs baseline: 3.4497x; 1.0141x over previous
//
#include <hip/hip_runtime.h>

// DilateAttention: B=4, d=384 (12 heads x 32), H=W=64, 3x3 taps, dilation 2, pad 2.
// f32 in / f32 out.
// v12: global_load_lds DMA staging — removes the register-bound in-flight-load
// ceiling that capped v1/v10/v11 at ~42-47 us.
// Ladder invariant: loads landing in VGPRs are limited to ~2-4 in flight by
// register headroom (v10: 152 cy/load eff.; v11 float4: 595 cy/load = fully
// serialized). global_load_lds needs NO landing regs: 1-KB DMAs queue deep on
// vmcnt and drain once per barrier.
// Structure: v1's proven block (4 rows x 64 x, grid 768, per-lane 128-B
// stores), 8x96 XCD swizzle. One 64-KB LDS buffer [32ch][8rows][64x] (linear
// in lane order — DMA dest is wave-uniform base + lane*16). k staged, QK from
// LDS, buffer reused for v (3 barriers total; softmax hides the v flight).
// Halo amplification 3x -> 2x. Plain launch_bounds (v7/v8 spill lesson).

#define NHD  12
#define DDIM 384
#define HH   64
#define WW   64
#define HWSZ 4096
#define SCALEF 0.17677669529663687f  // 1/sqrt(32)

__global__ __launch_bounds__(256) void dilate_attn(const float* __restrict__ q,
                                                   const float* __restrict__ k,
                                                   const float* __restrict__ v,
                                                   float* __restrict__ out) {
    __shared__ float buf[32 * 8 * 64];   // 65536 B: [ch][row][x], k then v

    const int tid = threadIdx.x;
    const int r   = tid >> 6;            // query row within block (wave id)
    const int x   = tid & 63;            // lane = x

    // XCD swizzle: 768 = 8 XCDs x 96 contiguous logical blocks (bijective).
    const int phys = blockIdx.x;
    const int lz   = (phys & 7) * 96 + (phys >> 3);
    const int bh   = lz >> 4;            // b*NH + n
    const int y0   = (lz & 15) * 4;
    const int y    = y0 + r;
    const int b    = bh / NHD;
    const int n    = bh - b * NHD;

    const int cbase = (b * DDIM + n * 32) * HWSZ;   // 32-bit element indexing
    const int pix   = y * WW + x;

    auto* lds0 = (__attribute__((address_space(3))) char*)buf;

    // Staging map: wave r issues instrs i=0..15; instr j=r*16+i moves 1 KB.
    // lane covers flat = j*64 + x; flat -> ch=flat>>7, row=(flat>>4)&7,
    // quad x4=(flat&15)*4. LDS byte = flat*16 (= uniform j*1024 + lane*16).
    const int flat0 = r * 1024 + x;

    // ---------------- issue k staging: 16 fire-and-forget DMAs/wave ---------
#pragma unroll
    for (int i = 0; i < 16; ++i) {
        const int flat = flat0 + i * 64;
        const int ch   = flat >> 7;
        const int row  = (flat >> 4) & 7;
        const int x4   = (flat & 15) << 2;
        int gy = y0 - 2 + row;                       // halo row, clamped (gated later)
        gy = gy < 0 ? 0 : (gy > 63 ? 63 : gy);
        const float* gsrc = k + cbase + ch * HWSZ + gy * WW + x4;
        __builtin_amdgcn_global_load_lds(
            (const __attribute__((address_space(1))) void*)gsrc,
            (__attribute__((address_space(3))) void*)(lds0 + (r * 16 + i) * 1024),
            16, 0, 0);
    }

    // ---------------- q preload (overlaps k DMA flight) ----------------
    float qreg[32];
#pragma unroll
    for (int c = 0; c < 32; ++c) qreg[c] = q[cbase + pix + c * HWSZ] * SCALEF;

    // ---------------- tap validity + clamped x (v1 gating semantics) --------
    bool vy[3];
#pragma unroll
    for (int di = 0; di < 3; ++di) {
        int yy = y + 2 * di - 2;
        vy[di] = (yy >= 0) && (yy < HH);
    }
    const int xm = (x >= 2)  ? x - 2 : 0;
    const int xp = (x <= 61) ? x + 2 : 63;
    bool tval[9];
#pragma unroll
    for (int di = 0; di < 3; ++di) {
        tval[di * 3 + 0] = vy[di] && (x >= 2);
        tval[di * 3 + 1] = vy[di];
        tval[di * 3 + 2] = vy[di] && (x <= 61);
    }

    __syncthreads();   // drains vmcnt: k (and q) landed

    // ---------------- Phase 1: logits from LDS (stride-1, conflict-free) ----
    float l[9];
#pragma unroll
    for (int t = 0; t < 9; ++t) l[t] = 0.f;
#pragma unroll
    for (int c = 0; c < 32; ++c) {
        const float qc = qreg[c];
        const float* cb = &buf[c * 512];
#pragma unroll
        for (int di = 0; di < 3; ++di) {
            const float* rowp = cb + (r + 2 * di) * 64;
            l[di * 3 + 0] += qc * rowp[xm];
            l[di * 3 + 1] += qc * rowp[x];
            l[di * 3 + 2] += qc * rowp[xp];
        }
    }

    __syncthreads();   // all k reads done -> buf reusable

    // ---------------- issue v staging into the same buffer ------------------
#pragma unroll
    for (int i = 0; i < 16; ++i) {
        const int flat = flat0 + i * 64;
        const int ch   = flat >> 7;
        const int row  = (flat >> 4) & 7;
        const int x4   = (flat & 15) << 2;
        int gy = y0 - 2 + row;
        gy = gy < 0 ? 0 : (gy > 63 ? 63 : gy);
        const float* gsrc = v + cbase + ch * HWSZ + gy * WW + x4;
        __builtin_amdgcn_global_load_lds(
            (const __attribute__((address_space(1))) void*)gsrc,
            (__attribute__((address_space(3))) void*)(lds0 + (r * 16 + i) * 1024),
            16, 0, 0);
    }

    // ---------------- softmax over 9 (hides v DMA flight) -------------------
#pragma unroll
    for (int t = 0; t < 9; ++t) l[t] = tval[t] ? l[t] : 0.f;  // zero-pad taps
    float m = l[0];
#pragma unroll
    for (int t = 1; t < 9; ++t) m = fmaxf(m, l[t]);
    float w[9], s = 0.f;
#pragma unroll
    for (int t = 0; t < 9; ++t) { w[t] = __expf(l[t] - m); s += w[t]; }
    float inv = 1.0f / s;
#pragma unroll
    for (int t = 0; t < 9; ++t) w[t] = tval[t] ? (w[t] * inv) : 0.f;  // padded V == 0

    __syncthreads();   // drains vmcnt: v landed

    // ---------------- Phase 2: weighted V from LDS; store per 4-ch group ----
    const int ob = (b * HH * WW + pix) * DDIM + n * 32;
#pragma unroll
    for (int cg = 0; cg < 8; ++cg) {
        float o4[4];
#pragma unroll
        for (int j = 0; j < 4; ++j) {
            const float* cb = &buf[(cg * 4 + j) * 512];
            float acc = 0.f;
#pragma unroll
            for (int di = 0; di < 3; ++di) {
                const float* rowp = cb + (r + 2 * di) * 64;
                acc += w[di * 3 + 0] * rowp[xm]
                     + w[di * 3 + 1] * rowp[x]
                     + w[di * 3 + 2] * rowp[xp];
            }
            o4[j] = acc;
        }
        // per-lane contiguous 128-B line overall (v1's proven store pattern)
        *(float4*)(out + ob + cg * 4) = make_float4(o4[0], o4[1], o4[2], o4[3]);
    }
}

extern "C" void kernel_launch(void* const* d_in, const int* in_sizes, int n_in,
                              void* d_out, int out_size, void* d_ws, size_t ws_size,
                              hipStream_t stream) {
    const float* q = (const float*)d_in[0];
    const float* k = (const float*)d_in[1];
    const float* v = (const float*)d_in[2];
    float* out = (float*)d_out;
    hipLaunchKernelGGL(dilate_attn, dim3(768), dim3(256), 0, stream, q, k, v, out);
}